// Round 2
// baseline (1948.658 us; speedup 1.0000x reference)
//
#include <hip/hip_runtime.h>
#include <hip/hip_bf16.h>
#include <hip/hip_cooperative_groups.h>
#include <math.h>

namespace cg = cooperative_groups;

// Problem constants
#define BATCH 64
#define TSTEP 20
#define FDIM  2048
#define EDIM  512
#define GDIM  1024
#define G3    3072
#define VDIM  32000

typedef __attribute__((ext_vector_type(8))) short short8x;
typedef __attribute__((ext_vector_type(4))) float f32x4;

static __device__ __forceinline__ unsigned short f2bf(float f) {
    unsigned int u = __float_as_uint(f);
    unsigned int r = (u + 0x7fffu + ((u >> 16) & 1u)) >> 16;
    return (unsigned short)r;
}
static __device__ __forceinline__ float bf2f(unsigned short u) {
    return __uint_as_float((unsigned int)u << 16);
}

// ---------------------------------------------------------------------------
// scale_img[e] = img_g[e]/||img_v[e,:]||  (512 rows, one wave each)
// ---------------------------------------------------------------------------
__global__ __launch_bounds__(256) void scales_img_kernel(
    const float* __restrict__ img_v, const float* __restrict__ img_g,
    float* __restrict__ scale_img)
{
    int wave = blockIdx.x * 4 + (threadIdx.x >> 6);
    int lane = threadIdx.x & 63;
    const float* row = img_v + (size_t)wave * FDIM;
    float s = 0.f;
    for (int k = lane; k < FDIM; k += 64) { float v = row[k]; s = fmaf(v, v, s); }
    for (int off = 32; off; off >>= 1) s += __shfl_down(s, off);
    if (lane == 0) scale_img[wave] = img_g[wave] * (1.0f / sqrtf(s));
}

// ---------------------------------------------------------------------------
// fc row norm + bf16 convert fused: one block per row of fc_v [V,1024]
// ---------------------------------------------------------------------------
__global__ __launch_bounds__(256) void fc_norm_cvt_kernel(
    const float* __restrict__ fc_v, const float* __restrict__ fc_g,
    short* __restrict__ v_bf, float* __restrict__ scale_fc)
{
    int row = blockIdx.x;
    int t = threadIdx.x;
    float4 v = ((const float4*)(fc_v + (size_t)row * GDIM))[t];
    short4 o;
    o.x = (short)f2bf(v.x); o.y = (short)f2bf(v.y);
    o.z = (short)f2bf(v.z); o.w = (short)f2bf(v.w);
    ((short4*)(v_bf + (size_t)row * GDIM))[t] = o;
    float ss = v.x * v.x + v.y * v.y + v.z * v.z + v.w * v.w;
    for (int off = 32; off; off >>= 1) ss += __shfl_down(ss, off);
    __shared__ float red[4];
    if ((t & 63) == 0) red[t >> 6] = ss;
    __syncthreads();
    if (t == 0) {
        float s = red[0] + red[1] + red[2] + red[3];
        scale_fc[row] = fc_g[row] * (1.0f / sqrtf(s));
    }
}

// ---------------------------------------------------------------------------
// generic fp32 -> bf16 convert (n must be divisible by 4)
// ---------------------------------------------------------------------------
__global__ __launch_bounds__(256) void cvt_bf16_kernel(
    const float* __restrict__ in, short* __restrict__ out, int n4)
{
    int i = blockIdx.x * 256 + threadIdx.x;
    if (i >= n4) return;
    float4 v = ((const float4*)in)[i];
    short4 o;
    o.x = (short)f2bf(v.x); o.y = (short)f2bf(v.y);
    o.z = (short)f2bf(v.z); o.w = (short)f2bf(v.w);
    ((short4*)out)[i] = o;
}

// ---------------------------------------------------------------------------
// img_embed: x_all[0][b][e] = dot(features[b,:], img_v[e,:]) * scale_img[e] + img_b[e]
// ---------------------------------------------------------------------------
__global__ __launch_bounds__(256) void img_embed_kernel(
    const float* __restrict__ features, const float* __restrict__ img_v,
    const float* __restrict__ scale_img, const float* __restrict__ img_b,
    float* __restrict__ x_all)
{
    int wave = blockIdx.x * 4 + (threadIdx.x >> 6);
    int lane = threadIdx.x & 63;
    int b = wave >> 9;
    int e = wave & 511;
    const float* frow = features + (size_t)b * FDIM;
    const float* vrow = img_v + (size_t)e * FDIM;
    float s = 0.f;
    for (int k = lane; k < FDIM; k += 64) s = fmaf(frow[k], vrow[k], s);
    for (int off = 32; off; off >>= 1) s += __shfl_down(s, off);
    if (lane == 0) x_all[b * EDIM + e] = s * scale_img[e] + img_b[e];
}

// ---------------------------------------------------------------------------
// gather: x_all[t][b][:] = emb_table[input_ids[b][t]] for t = 1..19
// ---------------------------------------------------------------------------
__global__ __launch_bounds__(256) void gather_kernel(
    const int* __restrict__ ids, const float* __restrict__ emb,
    float* __restrict__ x_all)
{
    int idx = blockIdx.x * 256 + threadIdx.x;
    int e = idx & 511;
    int b = (idx >> 9) & 63;
    int t = (idx >> 15) + 1;
    int id = ids[b * TSTEP + t];
    x_all[(size_t)(t * BATCH + b) * EDIM + e] = emb[(size_t)id * EDIM + e];
}

// ---------------------------------------------------------------------------
// bf16 MFMA GEMM, 128x128 tile (used for the gi GEMM)
// ---------------------------------------------------------------------------
__global__ __launch_bounds__(256) void mfma_gemm_kernel(
    const short* __restrict__ A, const short* __restrict__ B,
    float* __restrict__ C, int M, int N, int K,
    const float* __restrict__ scale, const float* __restrict__ bias,
    int out_mode)
{
    __shared__ short As[128 * 32];
    __shared__ short Bs[128 * 32];

    const int tid  = threadIdx.x;
    const int wave = tid >> 6;
    const int lane = tid & 63;
    const int m0 = blockIdx.y * 128;
    const int n0 = blockIdx.x * 128;

    const int srow   = lane >> 2;
    const int schunk = (lane & 3) ^ ((lane >> 3) & 3);

    const int wm = wave >> 1, wn = wave & 1;
    const int fr = lane & 15;
    const int q  = lane >> 4;
    const int kchunk = (q ^ ((fr >> 1) & 3)) * 8;

    f32x4 acc[4][4];
    #pragma unroll
    for (int i = 0; i < 4; ++i)
        #pragma unroll
        for (int j = 0; j < 4; ++j)
            acc[i][j] = (f32x4)(0.f);

    for (int k0 = 0; k0 < K; k0 += 32) {
        __syncthreads();
        #pragma unroll
        for (int p = 0; p < 2; ++p) {
            int mi = wave * 2 + p;
            int rA = mi * 16 + srow;
            const short* gA = A + (size_t)(m0 + rA) * K + k0 + schunk * 8;
            const short* gB = B + (size_t)(n0 + rA) * K + k0 + schunk * 8;
            __builtin_amdgcn_global_load_lds(
                (const __attribute__((address_space(1))) void*)gA,
                (__attribute__((address_space(3))) void*)(As + mi * 512), 16, 0, 0);
            __builtin_amdgcn_global_load_lds(
                (const __attribute__((address_space(1))) void*)gB,
                (__attribute__((address_space(3))) void*)(Bs + mi * 512), 16, 0, 0);
        }
        __syncthreads();

        short8x a[4], b[4];
        #pragma unroll
        for (int i = 0; i < 4; ++i)
            a[i] = *(const short8x*)(As + (wm * 64 + i * 16 + fr) * 32 + kchunk);
        #pragma unroll
        for (int j = 0; j < 4; ++j)
            b[j] = *(const short8x*)(Bs + (wn * 64 + j * 16 + fr) * 32 + kchunk);
        #pragma unroll
        for (int i = 0; i < 4; ++i)
            #pragma unroll
            for (int j = 0; j < 4; ++j)
                acc[i][j] = __builtin_amdgcn_mfma_f32_16x16x32_bf16(a[i], b[j], acc[i][j], 0, 0, 0);
    }

    #pragma unroll
    for (int i = 0; i < 4; ++i) {
        #pragma unroll
        for (int r = 0; r < 4; ++r) {
            int m = m0 + wm * 64 + i * 16 + q * 4 + r;
            #pragma unroll
            for (int j = 0; j < 4; ++j) {
                int n = n0 + wn * 64 + j * 16 + fr;
                float v = acc[i][j][r];
                if (scale) v *= scale[n];
                if (bias)  v += bias[n];
                if (out_mode == 0) {
                    C[(size_t)m * N + n] = v;
                } else {
                    C[(size_t)(m & 63) * (TSTEP * N) + (size_t)(m >> 6) * N + n] = v;
                }
            }
        }
    }
}

// ---------------------------------------------------------------------------
// bf16 MFMA GEMM, 256x256 tile, BK=64, 512 threads, 2-phase dbuf pipeline.
// (unchanged from round 1 -- known-good; 8-phase port is a future round)
// ---------------------------------------------------------------------------
__global__ __launch_bounds__(512, 2) void mfma_gemm256_kernel(
    const short* __restrict__ A, const short* __restrict__ B,
    float* __restrict__ C, int M, int N, int K,
    const float* __restrict__ scale, const float* __restrict__ bias,
    int out_mode)
{
    __shared__ short As[2][256 * 64];
    __shared__ short Bs[2][256 * 64];

    const int tid = threadIdx.x;
    const int mtiles = M >> 8;
    const int nwg = gridDim.x;

    int wgid;
    {
        int q = nwg >> 3, r = nwg & 7;
        int xcd = blockIdx.x & 7, idx = blockIdx.x >> 3;
        wgid = (xcd < r ? xcd * (q + 1) : r * (q + 1) + (xcd - r) * q) + idx;
    }
    const int mt = wgid % mtiles;
    const int nt = wgid / mtiles;
    const int m0 = mt << 8, n0 = nt << 8;

    const int schunk = (tid & 7) ^ ((tid >> 3) & 7);
    const short* gA = A + (size_t)(m0 + (tid >> 3)) * K + schunk * 8;
    const short* gB = B + (size_t)(n0 + (tid >> 3)) * K + schunk * 8;

    const int wv = tid >> 6, lane = tid & 63;
    const int sbase = wv * 512;

    const int wm = wv >> 2, wn = wv & 3;
    const int fr = lane & 15, qd = lane >> 4;
    const int key = fr & 7;
    int aoff[2], boff[2];
    #pragma unroll
    for (int kk = 0; kk < 2; ++kk) {
        int slot = ((kk << 2) | qd) ^ key;
        aoff[kk] = (wm * 128 + fr) * 64 + (slot << 3);
        boff[kk] = (wn * 64 + fr) * 64 + (slot << 3);
    }

    f32x4 acc[8][4];
    #pragma unroll
    for (int i = 0; i < 8; ++i)
        #pragma unroll
        for (int j = 0; j < 4; ++j)
            acc[i][j] = (f32x4)(0.f);

    auto stage = [&](int buf, int koff) {
        #pragma unroll
        for (int rho = 0; rho < 4; ++rho) {
            __builtin_amdgcn_global_load_lds(
                (const __attribute__((address_space(1))) void*)(gA + (size_t)(rho * 64) * K + koff),
                (__attribute__((address_space(3))) void*)(&As[buf][0] + rho * 4096 + sbase), 16, 0, 0);
            __builtin_amdgcn_global_load_lds(
                (const __attribute__((address_space(1))) void*)(gB + (size_t)(rho * 64) * K + koff),
                (__attribute__((address_space(3))) void*)(&Bs[buf][0] + rho * 4096 + sbase), 16, 0, 0);
        }
    };

    auto compute = [&](int buf) {
        const short* Ab = &As[buf][0];
        const short* Bb = &Bs[buf][0];
        #pragma unroll
        for (int kk = 0; kk < 2; ++kk) {
            short8x a[8], b[4];
            #pragma unroll
            for (int i = 0; i < 8; ++i) a[i] = *(const short8x*)(Ab + aoff[kk] + i * 1024);
            #pragma unroll
            for (int j = 0; j < 4; ++j) b[j] = *(const short8x*)(Bb + boff[kk] + j * 1024);
            __builtin_amdgcn_s_setprio(1);
            #pragma unroll
            for (int i = 0; i < 8; ++i)
                #pragma unroll
                for (int j = 0; j < 4; ++j)
                    acc[i][j] = __builtin_amdgcn_mfma_f32_16x16x32_bf16(a[i], b[j], acc[i][j], 0, 0, 0);
            __builtin_amdgcn_s_setprio(0);
        }
    };

    const int ksteps = K >> 6;
    stage(0, 0);
    __syncthreads();
    int cur = 0;
    for (int t = 0; t + 1 < ksteps; ++t) {
        stage(cur ^ 1, (t + 1) << 6);
        compute(cur);
        __syncthreads();
        cur ^= 1;
    }
    compute(cur);

    #pragma unroll
    for (int i = 0; i < 8; ++i) {
        #pragma unroll
        for (int r2 = 0; r2 < 4; ++r2) {
            int m = m0 + wm * 128 + i * 16 + qd * 4 + r2;
            size_t rowbase = (out_mode == 0)
                ? (size_t)m * N
                : (size_t)(m & 63) * (TSTEP * N) + (size_t)(m >> 6) * N;
            #pragma unroll
            for (int j = 0; j < 4; ++j) {
                int n = n0 + wn * 64 + j * 16 + fr;
                float v = acc[i][j][r2];
                if (scale) v *= scale[n];
                if (bias)  v += bias[n];
                C[rowbase + n] = v;
            }
        }
    }
}

// ===========================================================================
// GRU via split-bf16 MFMA.
//   gh = h @ W_hh^T computed as concat-GEMM: A=[h1|h1|h2] (64x3072 bf16),
//   B=[W1|W2|W1] (3072x3072 bf16 rows), error ~2^-16 (fp32-equivalent).
// Block (jt,ks): jt in 0..63 (16 j's, all 3 gates), ks in 0..3 (768 k-cols).
// B-tile 48x768 bf16 staged in LDS (rows padded to 776 shorts -> 2-way bank
// aliasing = free), split computed on the fly from fp32 W_hh.
// 8 waves: mt = wv&3 (16 A-rows), kh = wv>>2 (384-k half); kh=1 partials
// reduced into kh=0 via LDS. gh_part[ks][64][3072] fp32 written to global.
// ew phase: 1 thread per (b,j): sums 4 ks-partials deterministically, gates,
// writes hcur (fp32), a_buf (h1,h1,h2 bf16) and hs_bf (bf16 h for fc GEMM).
// ===========================================================================

// ---- shared device pieces -------------------------------------------------
struct GruWaveCtx {
    const short* aptr;
    const short* b0p; const short* b1p; const short* b2p;
    int mt, kh, fr, q, jt, ks;
};

static __device__ __forceinline__ void gru_stage_B(
    short* Bs, const float* __restrict__ W_hh, int jt, int ks, int tid)
{
    for (int idx = tid; idx < 48 * 96; idx += 512) {
        int r = idx / 96, c8 = idx - r * 96;
        int g = r >> 4, jl = r & 15;
        int jrow = g * 1024 + jt * 16 + jl;
        int c0 = ks * 768 + c8 * 8;
        int seg = c0 >> 10;          // 0:W1  1:W2  2:W1
        int k0 = c0 & 1023;
        const float* wp = W_hh + (size_t)jrow * 1024 + k0;
        float4 wa = *(const float4*)(wp);
        float4 wb = *(const float4*)(wp + 4);
        float w[8] = {wa.x, wa.y, wa.z, wa.w, wb.x, wb.y, wb.z, wb.w};
        short* dst = Bs + r * 776 + c8 * 8;
        #pragma unroll
        for (int i = 0; i < 8; ++i) {
            unsigned short u1 = f2bf(w[i]);
            unsigned short u = u1;
            if (seg == 1) u = f2bf(w[i] - bf2f(u1));
            dst[i] = (short)u;
        }
    }
}

static __device__ __forceinline__ void gru_gemm_phase(
    const short* Bs, float* red, const short* __restrict__ a_buf,
    float* __restrict__ gh_part, int tid, int jt, int ks)
{
    const int wv = tid >> 6, lane = tid & 63;
    const int mt = wv & 3, kh = wv >> 2;
    const int fr = lane & 15, q = lane >> 4;
    const int kbase = kh * 384;
    const short* aptr = a_buf + (size_t)(mt * 16 + fr) * 3072 + ks * 768 + kbase + q * 8;
    const short* b0p = Bs + (fr) * 776 + kbase + q * 8;
    const short* b1p = Bs + (16 + fr) * 776 + kbase + q * 8;
    const short* b2p = Bs + (32 + fr) * 776 + kbase + q * 8;

    f32x4 a0 = (f32x4)(0.f), a1 = (f32x4)(0.f), a2 = (f32x4)(0.f);
    #pragma unroll
    for (int kk = 0; kk < 12; ++kk) {
        short8x av  = *(const short8x*)(aptr + kk * 32);
        short8x bv0 = *(const short8x*)(b0p + kk * 32);
        short8x bv1 = *(const short8x*)(b1p + kk * 32);
        short8x bv2 = *(const short8x*)(b2p + kk * 32);
        a0 = __builtin_amdgcn_mfma_f32_16x16x32_bf16(av, bv0, a0, 0, 0, 0);
        a1 = __builtin_amdgcn_mfma_f32_16x16x32_bf16(av, bv1, a1, 0, 0, 0);
        a2 = __builtin_amdgcn_mfma_f32_16x16x32_bf16(av, bv2, a2, 0, 0, 0);
    }
    if (kh == 1) {
        #pragma unroll
        for (int r = 0; r < 4; ++r) {
            red[(mt * 3 + 0) * 256 + lane * 4 + r] = a0[r];
            red[(mt * 3 + 1) * 256 + lane * 4 + r] = a1[r];
            red[(mt * 3 + 2) * 256 + lane * 4 + r] = a2[r];
        }
    }
    __syncthreads();
    if (kh == 0) {
        #pragma unroll
        for (int r = 0; r < 4; ++r) {
            float v0 = a0[r] + red[(mt * 3 + 0) * 256 + lane * 4 + r];
            float v1 = a1[r] + red[(mt * 3 + 1) * 256 + lane * 4 + r];
            float v2 = a2[r] + red[(mt * 3 + 2) * 256 + lane * 4 + r];
            int b = mt * 16 + q * 4 + r;
            size_t base = (size_t)ks * (64 * G3) + (size_t)b * G3 + jt * 16 + fr;
            gh_part[base]          = v0;
            gh_part[base + 1024]   = v1;
            gh_part[base + 2048]   = v2;
        }
    }
}

static __device__ __forceinline__ void gru_ew_elem(
    int o, const float* __restrict__ gh_part, const float* __restrict__ gi_t,
    const float* __restrict__ b_hh, float* __restrict__ hcur,
    short* __restrict__ a_buf, short* __restrict__ hs_t)
{
    int b = o >> 10, j = o & 1023;
    const float* gp = gh_part + (size_t)b * G3 + j;
    const size_t slab = (size_t)64 * G3;
    float hr = gp[0] + gp[slab] + gp[2 * slab] + gp[3 * slab];
    float hz = gp[1024] + gp[slab + 1024] + gp[2 * slab + 1024] + gp[3 * slab + 1024];
    float hn = gp[2048] + gp[slab + 2048] + gp[2 * slab + 2048] + gp[3 * slab + 2048];
    hr += b_hh[j]; hz += b_hh[1024 + j]; hn += b_hh[2048 + j];
    const float* gi = gi_t + (size_t)b * G3 + j;
    float ir = gi[0], iz = gi[1024], in_ = gi[2048];
    float rg = 1.f / (1.f + expf(-(ir + hr)));
    float zg = 1.f / (1.f + expf(-(iz + hz)));
    float ng = tanhf(in_ + rg * hn);
    float h_new = (1.f - zg) * ng + zg * hcur[b * GDIM + j];
    hcur[b * GDIM + j] = h_new;
    unsigned short h1 = f2bf(h_new);
    unsigned short h2 = f2bf(h_new - bf2f(h1));
    short* ab = a_buf + (size_t)b * G3;
    ab[j] = (short)h1; ab[1024 + j] = (short)h1; ab[2048 + j] = (short)h2;
    hs_t[(size_t)b * GDIM + j] = (short)h1;
}

// ---- persistent cooperative kernel (preferred path) -----------------------
__global__ __launch_bounds__(512, 1) void gru_persist_kernel(
    const float* __restrict__ W_hh, const float* __restrict__ gi_all,
    const float* __restrict__ b_hh, float* __restrict__ hcur,
    short* __restrict__ a_buf, float* __restrict__ gh_part,
    short* __restrict__ hs_bf)
{
    __shared__ short Bs[48 * 776];
    __shared__ float red[12 * 256];

    const int tid = threadIdx.x;
    const int bid = blockIdx.x;
    const int jt = bid >> 2;
    const int ks = bid & 3;
    cg::grid_group grid = cg::this_grid();

    gru_stage_B(Bs, W_hh, jt, ks, tid);
    __syncthreads();

    for (int t = 0; t < TSTEP; ++t) {
        gru_gemm_phase(Bs, red, a_buf, gh_part, tid, jt, ks);
        grid.sync();
        if (tid < 256) {
            int o = bid * 256 + tid;
            gru_ew_elem(o, gh_part, gi_all + (size_t)t * BATCH * G3, b_hh,
                        hcur, a_buf, hs_bf + (size_t)t * BATCH * GDIM);
        }
        grid.sync();
    }
}

// ---- fallback path: 2 plain launches per step -----------------------------
__global__ __launch_bounds__(512) void gru_gemm_step_kernel(
    const float* __restrict__ W_hh, const short* __restrict__ a_buf,
    float* __restrict__ gh_part)
{
    __shared__ short Bs[48 * 776];
    __shared__ float red[12 * 256];
    const int tid = threadIdx.x;
    const int jt = blockIdx.x >> 2;
    const int ks = blockIdx.x & 3;
    gru_stage_B(Bs, W_hh, jt, ks, tid);
    __syncthreads();
    gru_gemm_phase(Bs, red, a_buf, gh_part, tid, jt, ks);
}

__global__ __launch_bounds__(256) void gru_ew_step_kernel(
    const float* __restrict__ gh_part, const float* __restrict__ gi_t,
    const float* __restrict__ b_hh, float* __restrict__ hcur,
    short* __restrict__ a_buf, short* __restrict__ hs_t)
{
    int o = blockIdx.x * 256 + threadIdx.x;
    gru_ew_elem(o, gh_part, gi_t, b_hh, hcur, a_buf, hs_t);
}

// ---------------------------------------------------------------------------
// launch
// ---------------------------------------------------------------------------
extern "C" void kernel_launch(void* const* d_in, const int* in_sizes, int n_in,
                              void* d_out, int out_size, void* d_ws, size_t ws_size,
                              hipStream_t stream)
{
    const float* features = (const float*)d_in[0];
    const int*   ids      = (const int*)  d_in[1];
    const float* emb      = (const float*)d_in[2];
    const float* img_v    = (const float*)d_in[3];
    const float* img_g    = (const float*)d_in[4];
    const float* img_b    = (const float*)d_in[5];
    const float* W_ih     = (const float*)d_in[6];
    const float* W_hh     = (const float*)d_in[7];
    const float* b_ih     = (const float*)d_in[8];
    const float* b_hh     = (const float*)d_in[9];
    const float* fc_v     = (const float*)d_in[10];
    const float* fc_g     = (const float*)d_in[11];
    const float* fc_b     = (const float*)d_in[12];
    float* out = (float*)d_out;
    float* ws  = (float*)d_ws;

    // workspace layout (float offsets)
    float* scale_img = ws;                          //       512
    float* scale_fc  = ws + 512;                    //    32,000
    short* hs_bf     = (short*)(ws + 32512);        // 1,310,720 sh (655,360 f)
    float* hcur      = ws + 687872;                 //    65,536
    short* a_buf     = (short*)(ws + 753408);       //   196,608 sh (98,304 f)
    float* gh_part   = ws + 851712;                 //   786,432  [4][64][3072]
    float* x_all     = ws + 1638144;                //   655,360  [20][64][512]
    short* x_bf      = (short*)(ws + 2293504);      //   655,360 sh
    short* wih_bf    = (short*)(ws + 2621184);      // 3,145,728 sh
    float* gi_all    = ws + 4194048;                // 3,932,160  [1280][3072]
    // fcv_bf overlays gh_part..gi_all (all dead after GRU): peak 68.9 MiB
    short* fcv_bf    = (short*)(ws + 851712);       // 32,768,000 sh

    hipLaunchKernelGGL(scales_img_kernel, dim3(128), dim3(256), 0, stream,
                       img_v, img_g, scale_img);
    hipLaunchKernelGGL(img_embed_kernel, dim3(8192), dim3(256), 0, stream,
                       features, img_v, scale_img, img_b, x_all);
    hipLaunchKernelGGL(gather_kernel, dim3(2432), dim3(256), 0, stream,
                       ids, emb, x_all);
    hipLaunchKernelGGL(cvt_bf16_kernel, dim3((TSTEP * BATCH * EDIM / 4 + 255) / 256), dim3(256), 0, stream,
                       x_all, x_bf, TSTEP * BATCH * EDIM / 4);
    hipLaunchKernelGGL(cvt_bf16_kernel, dim3((G3 * EDIM / 4 + 255) / 256), dim3(256), 0, stream,
                       W_ih, wih_bf, G3 * EDIM / 4);
    hipMemsetAsync(hcur, 0, (size_t)BATCH * GDIM * sizeof(float), stream);
    hipMemsetAsync(a_buf, 0, (size_t)BATCH * G3 * sizeof(short), stream);

    // gi_all = x_bf @ wih_bf^T + b_ih   [1280, 3072]
    hipLaunchKernelGGL(mfma_gemm_kernel, dim3(G3 / 128, (TSTEP * BATCH) / 128, 1), dim3(256), 0, stream,
                       x_bf, wih_bf, gi_all, TSTEP * BATCH, G3, EDIM,
                       (const float*)nullptr, b_ih, 0);

    // GRU recurrence: persistent cooperative kernel (fallback: 2 launches/step)
    {
        const float* W_hh_a = W_hh; const float* gi_a = gi_all;
        const float* bhh_a = b_hh; float* hcur_a = hcur;
        short* abuf_a = a_buf; float* ghp_a = gh_part; short* hsbf_a = hs_bf;
        void* args[] = {(void*)&W_hh_a, (void*)&gi_a, (void*)&bhh_a,
                        (void*)&hcur_a, (void*)&abuf_a, (void*)&ghp_a,
                        (void*)&hsbf_a};
        hipError_t e = hipLaunchCooperativeKernel(
            (const void*)gru_persist_kernel, dim3(256), dim3(512), args, 0, stream);
        if (e != hipSuccess) {
            for (int t = 0; t < TSTEP; ++t) {
                hipLaunchKernelGGL(gru_gemm_step_kernel, dim3(256), dim3(512), 0, stream,
                                   W_hh, a_buf, gh_part);
                hipLaunchKernelGGL(gru_ew_step_kernel, dim3(256), dim3(256), 0, stream,
                                   gh_part, gi_all + (size_t)t * BATCH * G3, b_hh,
                                   hcur, a_buf, hs_bf + (size_t)t * BATCH * GDIM);
            }
        }
    }

    // fc_v norms + bf16 convert (after GRU: fcv_bf overlays dead region)
    hipLaunchKernelGGL(fc_norm_cvt_kernel, dim3(VDIM), dim3(256), 0, stream,
                       fc_v, fc_g, fcv_bf, scale_fc);

    // preds = (hs_bf @ fcv_bf^T) * scale_fc + fc_b, permuted [B,T,V] store
    hipLaunchKernelGGL(mfma_gemm256_kernel,
                       dim3((VDIM / 256) * ((TSTEP * BATCH) / 256)), dim3(512), 0, stream,
                       hs_bf, fcv_bf, out, TSTEP * BATCH, VDIM, GDIM,
                       scale_fc, fc_b, 1);
}

// Round 3
// 943.420 us; speedup vs baseline: 2.0655x; 2.0655x over previous
//
#include <hip/hip_runtime.h>
#include <hip/hip_bf16.h>
#include <math.h>

// Problem constants
#define BATCH 64
#define TSTEP 20
#define FDIM  2048
#define EDIM  512
#define GDIM  1024
#define G3    3072
#define VDIM  32000

typedef __attribute__((ext_vector_type(8))) short short8x;
typedef __attribute__((ext_vector_type(4))) float f32x4;

static __device__ __forceinline__ unsigned short f2bf(float f) {
    unsigned int u = __float_as_uint(f);
    unsigned int r = (u + 0x7fffu + ((u >> 16) & 1u)) >> 16;
    return (unsigned short)r;
}
static __device__ __forceinline__ float bf2f(unsigned short u) {
    return __uint_as_float((unsigned int)u << 16);
}

// ---------------------------------------------------------------------------
// scale_img[e] = img_g[e]/||img_v[e,:]||  (512 rows, one wave each)
// ---------------------------------------------------------------------------
__global__ __launch_bounds__(256) void scales_img_kernel(
    const float* __restrict__ img_v, const float* __restrict__ img_g,
    float* __restrict__ scale_img)
{
    int wave = blockIdx.x * 4 + (threadIdx.x >> 6);
    int lane = threadIdx.x & 63;
    const float* row = img_v + (size_t)wave * FDIM;
    float s = 0.f;
    for (int k = lane; k < FDIM; k += 64) { float v = row[k]; s = fmaf(v, v, s); }
    for (int off = 32; off; off >>= 1) s += __shfl_down(s, off);
    if (lane == 0) scale_img[wave] = img_g[wave] * (1.0f / sqrtf(s));
}

// ---------------------------------------------------------------------------
// fc row norm + bf16 convert fused: one block per row of fc_v [V,1024]
// ---------------------------------------------------------------------------
__global__ __launch_bounds__(256) void fc_norm_cvt_kernel(
    const float* __restrict__ fc_v, const float* __restrict__ fc_g,
    short* __restrict__ v_bf, float* __restrict__ scale_fc)
{
    int row = blockIdx.x;
    int t = threadIdx.x;
    float4 v = ((const float4*)(fc_v + (size_t)row * GDIM))[t];
    short4 o;
    o.x = (short)f2bf(v.x); o.y = (short)f2bf(v.y);
    o.z = (short)f2bf(v.z); o.w = (short)f2bf(v.w);
    ((short4*)(v_bf + (size_t)row * GDIM))[t] = o;
    float ss = v.x * v.x + v.y * v.y + v.z * v.z + v.w * v.w;
    for (int off = 32; off; off >>= 1) ss += __shfl_down(ss, off);
    __shared__ float red[4];
    if ((t & 63) == 0) red[t >> 6] = ss;
    __syncthreads();
    if (t == 0) {
        float s = red[0] + red[1] + red[2] + red[3];
        scale_fc[row] = fc_g[row] * (1.0f / sqrtf(s));
    }
}

// ---------------------------------------------------------------------------
// generic fp32 -> bf16 convert (n must be divisible by 4)
// ---------------------------------------------------------------------------
__global__ __launch_bounds__(256) void cvt_bf16_kernel(
    const float* __restrict__ in, short* __restrict__ out, int n4)
{
    int i = blockIdx.x * 256 + threadIdx.x;
    if (i >= n4) return;
    float4 v = ((const float4*)in)[i];
    short4 o;
    o.x = (short)f2bf(v.x); o.y = (short)f2bf(v.y);
    o.z = (short)f2bf(v.z); o.w = (short)f2bf(v.w);
    ((short4*)out)[i] = o;
}

// ---------------------------------------------------------------------------
// Bcat precompute: Bcat[j] = [W1[j,:] | W1[j,:] | W2[j,:]] (bf16 split of W_hh)
// W1 = bf16(W), W2 = bf16(W - W1). One thread per 4 cols of W.
// ---------------------------------------------------------------------------
__global__ __launch_bounds__(256) void wcat_kernel(
    const float* __restrict__ W_hh, short* __restrict__ Bcat)
{
    int idx = blockIdx.x * 256 + threadIdx.x;   // 3072 * 256
    int j = idx >> 8;
    int k = (idx & 255) << 2;
    float4 w = *(const float4*)(W_hh + (size_t)j * GDIM + k);
    short4 s1, s2;
    s1.x = (short)f2bf(w.x); s2.x = (short)f2bf(w.x - bf2f((unsigned short)s1.x));
    s1.y = (short)f2bf(w.y); s2.y = (short)f2bf(w.y - bf2f((unsigned short)s1.y));
    s1.z = (short)f2bf(w.z); s2.z = (short)f2bf(w.z - bf2f((unsigned short)s1.z));
    s1.w = (short)f2bf(w.w); s2.w = (short)f2bf(w.w - bf2f((unsigned short)s1.w));
    short* row = Bcat + (size_t)j * G3;
    *(short4*)(row + k)        = s1;
    *(short4*)(row + 1024 + k) = s1;
    *(short4*)(row + 2048 + k) = s2;
}

// ---------------------------------------------------------------------------
// img_embed: x_all[0][b][e] = dot(features[b,:], img_v[e,:]) * scale_img[e] + img_b[e]
// ---------------------------------------------------------------------------
__global__ __launch_bounds__(256) void img_embed_kernel(
    const float* __restrict__ features, const float* __restrict__ img_v,
    const float* __restrict__ scale_img, const float* __restrict__ img_b,
    float* __restrict__ x_all)
{
    int wave = blockIdx.x * 4 + (threadIdx.x >> 6);
    int lane = threadIdx.x & 63;
    int b = wave >> 9;
    int e = wave & 511;
    const float* frow = features + (size_t)b * FDIM;
    const float* vrow = img_v + (size_t)e * FDIM;
    float s = 0.f;
    for (int k = lane; k < FDIM; k += 64) s = fmaf(frow[k], vrow[k], s);
    for (int off = 32; off; off >>= 1) s += __shfl_down(s, off);
    if (lane == 0) x_all[b * EDIM + e] = s * scale_img[e] + img_b[e];
}

// ---------------------------------------------------------------------------
// gather: x_all[t][b][:] = emb_table[input_ids[b][t]] for t = 1..19
// ---------------------------------------------------------------------------
__global__ __launch_bounds__(256) void gather_kernel(
    const int* __restrict__ ids, const float* __restrict__ emb,
    float* __restrict__ x_all)
{
    int idx = blockIdx.x * 256 + threadIdx.x;
    int e = idx & 511;
    int b = (idx >> 9) & 63;
    int t = (idx >> 15) + 1;
    int id = ids[b * TSTEP + t];
    x_all[(size_t)(t * BATCH + b) * EDIM + e] = emb[(size_t)id * EDIM + e];
}

// ---------------------------------------------------------------------------
// bf16 MFMA GEMM, 128x128 tile (used for the gi GEMM)
// ---------------------------------------------------------------------------
__global__ __launch_bounds__(256) void mfma_gemm_kernel(
    const short* __restrict__ A, const short* __restrict__ B,
    float* __restrict__ C, int M, int N, int K,
    const float* __restrict__ scale, const float* __restrict__ bias,
    int out_mode)
{
    __shared__ short As[128 * 32];
    __shared__ short Bs[128 * 32];

    const int tid  = threadIdx.x;
    const int wave = tid >> 6;
    const int lane = tid & 63;
    const int m0 = blockIdx.y * 128;
    const int n0 = blockIdx.x * 128;

    const int srow   = lane >> 2;
    const int schunk = (lane & 3) ^ ((lane >> 3) & 3);

    const int wm = wave >> 1, wn = wave & 1;
    const int fr = lane & 15;
    const int q  = lane >> 4;
    const int kchunk = (q ^ ((fr >> 1) & 3)) * 8;

    f32x4 acc[4][4];
    #pragma unroll
    for (int i = 0; i < 4; ++i)
        #pragma unroll
        for (int j = 0; j < 4; ++j)
            acc[i][j] = (f32x4)(0.f);

    for (int k0 = 0; k0 < K; k0 += 32) {
        __syncthreads();
        #pragma unroll
        for (int p = 0; p < 2; ++p) {
            int mi = wave * 2 + p;
            int rA = mi * 16 + srow;
            const short* gA = A + (size_t)(m0 + rA) * K + k0 + schunk * 8;
            const short* gB = B + (size_t)(n0 + rA) * K + k0 + schunk * 8;
            __builtin_amdgcn_global_load_lds(
                (const __attribute__((address_space(1))) void*)gA,
                (__attribute__((address_space(3))) void*)(As + mi * 512), 16, 0, 0);
            __builtin_amdgcn_global_load_lds(
                (const __attribute__((address_space(1))) void*)gB,
                (__attribute__((address_space(3))) void*)(Bs + mi * 512), 16, 0, 0);
        }
        __syncthreads();

        short8x a[4], b[4];
        #pragma unroll
        for (int i = 0; i < 4; ++i)
            a[i] = *(const short8x*)(As + (wm * 64 + i * 16 + fr) * 32 + kchunk);
        #pragma unroll
        for (int j = 0; j < 4; ++j)
            b[j] = *(const short8x*)(Bs + (wn * 64 + j * 16 + fr) * 32 + kchunk);
        #pragma unroll
        for (int i = 0; i < 4; ++i)
            #pragma unroll
            for (int j = 0; j < 4; ++j)
                acc[i][j] = __builtin_amdgcn_mfma_f32_16x16x32_bf16(a[i], b[j], acc[i][j], 0, 0, 0);
    }

    #pragma unroll
    for (int i = 0; i < 4; ++i) {
        #pragma unroll
        for (int r = 0; r < 4; ++r) {
            int m = m0 + wm * 64 + i * 16 + q * 4 + r;
            #pragma unroll
            for (int j = 0; j < 4; ++j) {
                int n = n0 + wn * 64 + j * 16 + fr;
                float v = acc[i][j][r];
                if (scale) v *= scale[n];
                if (bias)  v += bias[n];
                if (out_mode == 0) {
                    C[(size_t)m * N + n] = v;
                } else {
                    C[(size_t)(m & 63) * (TSTEP * N) + (size_t)(m >> 6) * N + n] = v;
                }
            }
        }
    }
}

// ---------------------------------------------------------------------------
// bf16 MFMA GEMM, 256x256 tile, BK=64, 512 threads, 2-buffer pipeline with
// COUNTED vmcnt (T4): stage(t+1) issued before compute(t); wait only for
// stage(t)'s 8 loads (vmcnt(8)) then raw s_barrier -- stage(t+1)'s loads stay
// in flight across the barrier. sched_barrier(0) pins phase boundaries.
// ---------------------------------------------------------------------------
__global__ __launch_bounds__(512, 2) void mfma_gemm256_kernel(
    const short* __restrict__ A, const short* __restrict__ B,
    float* __restrict__ C, int M, int N, int K,
    const float* __restrict__ scale, const float* __restrict__ bias,
    int out_mode)
{
    __shared__ short As[2][256 * 64];
    __shared__ short Bs[2][256 * 64];

    const int tid = threadIdx.x;
    const int mtiles = M >> 8;
    const int nwg = gridDim.x;

    int wgid;
    {
        int q = nwg >> 3, r = nwg & 7;
        int xcd = blockIdx.x & 7, idx = blockIdx.x >> 3;
        wgid = (xcd < r ? xcd * (q + 1) : r * (q + 1) + (xcd - r) * q) + idx;
    }
    const int mt = wgid % mtiles;
    const int nt = wgid / mtiles;
    const int m0 = mt << 8, n0 = nt << 8;

    const int schunk = (tid & 7) ^ ((tid >> 3) & 7);
    const short* gA = A + (size_t)(m0 + (tid >> 3)) * K + schunk * 8;
    const short* gB = B + (size_t)(n0 + (tid >> 3)) * K + schunk * 8;

    const int wv = tid >> 6, lane = tid & 63;
    const int sbase = wv * 512;

    const int wm = wv >> 2, wn = wv & 3;
    const int fr = lane & 15, qd = lane >> 4;
    const int key = fr & 7;
    int aoff[2], boff[2];
    #pragma unroll
    for (int kk = 0; kk < 2; ++kk) {
        int slot = ((kk << 2) | qd) ^ key;
        aoff[kk] = (wm * 128 + fr) * 64 + (slot << 3);
        boff[kk] = (wn * 64 + fr) * 64 + (slot << 3);
    }

    f32x4 acc[8][4];
    #pragma unroll
    for (int i = 0; i < 8; ++i)
        #pragma unroll
        for (int j = 0; j < 4; ++j)
            acc[i][j] = (f32x4)(0.f);

    auto stage = [&](int buf, int koff) {
        #pragma unroll
        for (int rho = 0; rho < 4; ++rho) {
            __builtin_amdgcn_global_load_lds(
                (const __attribute__((address_space(1))) void*)(gA + (size_t)(rho * 64) * K + koff),
                (__attribute__((address_space(3))) void*)(&As[buf][0] + rho * 4096 + sbase), 16, 0, 0);
            __builtin_amdgcn_global_load_lds(
                (const __attribute__((address_space(1))) void*)(gB + (size_t)(rho * 64) * K + koff),
                (__attribute__((address_space(3))) void*)(&Bs[buf][0] + rho * 4096 + sbase), 16, 0, 0);
        }
    };

    auto compute = [&](int buf) {
        const short* Ab = &As[buf][0];
        const short* Bb = &Bs[buf][0];
        #pragma unroll
        for (int kk = 0; kk < 2; ++kk) {
            short8x a[8], b[4];
            #pragma unroll
            for (int i = 0; i < 8; ++i) a[i] = *(const short8x*)(Ab + aoff[kk] + i * 1024);
            #pragma unroll
            for (int j = 0; j < 4; ++j) b[j] = *(const short8x*)(Bb + boff[kk] + j * 1024);
            __builtin_amdgcn_s_setprio(1);
            #pragma unroll
            for (int i = 0; i < 8; ++i)
                #pragma unroll
                for (int j = 0; j < 4; ++j)
                    acc[i][j] = __builtin_amdgcn_mfma_f32_16x16x32_bf16(a[i], b[j], acc[i][j], 0, 0, 0);
            __builtin_amdgcn_s_setprio(0);
        }
    };

    const int ksteps = K >> 6;
    stage(0, 0);
    int cur = 0;
    for (int t = 0; t < ksteps; ++t) {
        if (t + 1 < ksteps) {
            stage(cur ^ 1, (t + 1) << 6);
            asm volatile("s_waitcnt vmcnt(8)" ::: "memory");
        } else {
            asm volatile("s_waitcnt vmcnt(0)" ::: "memory");
        }
        __builtin_amdgcn_s_barrier();
        __builtin_amdgcn_sched_barrier(0);
        compute(cur);
        __builtin_amdgcn_sched_barrier(0);
        __builtin_amdgcn_s_barrier();
        cur ^= 1;
    }

    #pragma unroll
    for (int i = 0; i < 8; ++i) {
        #pragma unroll
        for (int r2 = 0; r2 < 4; ++r2) {
            int m = m0 + wm * 128 + i * 16 + qd * 4 + r2;
            size_t rowbase = (out_mode == 0)
                ? (size_t)m * N
                : (size_t)(m & 63) * (TSTEP * N) + (size_t)(m >> 6) * N;
            #pragma unroll
            for (int j = 0; j < 4; ++j) {
                int n = n0 + wn * 64 + j * 16 + fr;
                float v = acc[i][j][r2];
                if (scale) v *= scale[n];
                if (bias)  v += bias[n];
                C[rowbase + n] = v;
            }
        }
    }
}

// ===========================================================================
// Fused GRU step, one launch per t, no cross-block dependency.
// gh = h @ W_hh^T via split-bf16: A = [h1|h2|h1] (64x3072), Bcat = [W1|W1|W2].
// Grid 64 blocks x 256 threads. Block owns 16 j's x 3 gates = 48 Bcat rows:
// r_b = g*16 + jl -> output col c = g*16 + fr, so after the K-loop each lane
// holds all 3 gates of its (b = mt*16+q*4+r, jj = fr) IN REGISTERS -> gate
// elementwise fused with zero LDS roundtrip and zero cross-block traffic.
// 3-buffer LDS pipeline (BK=128, 28KB/buf) with counted vmcnt (2 stages in
// flight). XOR chunk swizzle slot^(row&15) both-sides for conflict-free
// ds_read_b128. h handoff across steps via a_in/a_out ping-pong (race-free).
// ===========================================================================
__global__ __launch_bounds__(256) void gru_step3_kernel(
    const short* __restrict__ Bcat, const short* __restrict__ a_in,
    short* __restrict__ a_out, const float* __restrict__ gi_t,
    const float* __restrict__ b_hh, float* __restrict__ hcur,
    short* __restrict__ hs_t)
{
    __shared__ short lds[3 * 14336];   // 3 x 28KB: [A 64x128 | B 48x128]

    const int tid = threadIdx.x;
    const int js = blockIdx.x << 4;    // 16 j's per block
    const int wv = tid >> 6, lane = tid & 63;
    const int mt = wv;                 // 4 waves = 4 m-tiles (16 batches each)
    const int fr = lane & 15, q = lane >> 4;

    // staging source pointers: 7 chunks of 16B per thread per K-tile
    const short* srcp[7];
    #pragma unroll
    for (int i = 0; i < 7; ++i) {
        int c = tid + (i << 8);
        int row = c >> 4, slot = c & 15;
        if (row < 64) {
            srcp[i] = a_in + (size_t)row * G3 + ((slot ^ (row & 15)) << 3);
        } else {
            int rb = row - 64, g = rb >> 4, jl = rb & 15;
            srcp[i] = Bcat + (size_t)(g * GDIM + js + jl) * G3 + ((slot ^ (rb & 15)) << 3);
        }
    }

    // fragment read offsets (shorts)
    int aoff[4], boff[3][4];
    #pragma unroll
    for (int kk = 0; kk < 4; ++kk) {
        int slot = ((kk << 2) | q) ^ fr;
        aoff[kk] = (mt * 16 + fr) * 128 + (slot << 3);
        #pragma unroll
        for (int g = 0; g < 3; ++g)
            boff[g][kk] = 8192 + (g * 16 + fr) * 128 + (slot << 3);
    }

    f32x4 acc[3];
    acc[0] = (f32x4)(0.f); acc[1] = (f32x4)(0.f); acc[2] = (f32x4)(0.f);

    auto stageG = [&](int bb, int kb) {
        #pragma unroll
        for (int i = 0; i < 7; ++i) {
            __builtin_amdgcn_global_load_lds(
                (const __attribute__((address_space(1))) void*)(srcp[i] + kb),
                (__attribute__((address_space(3))) void*)(lds + bb + (((wv << 6) + (i << 8)) << 3)),
                16, 0, 0);
        }
    };

    auto computeG = [&](int bb) {
        const short* L = lds + bb;
        __builtin_amdgcn_s_setprio(1);
        #pragma unroll
        for (int kk = 0; kk < 4; ++kk) {
            short8x av = *(const short8x*)(L + aoff[kk]);
            #pragma unroll
            for (int g = 0; g < 3; ++g) {
                short8x bv = *(const short8x*)(L + boff[g][kk]);
                acc[g] = __builtin_amdgcn_mfma_f32_16x16x32_bf16(av, bv, acc[g], 0, 0, 0);
            }
        }
        __builtin_amdgcn_s_setprio(0);
    };

    const int bufOff[3] = {0, 14336, 28672};
    stageG(bufOff[0], 0);
    stageG(bufOff[1], 128);
    const int ksteps = 24;             // 3072 / 128
    for (int t = 0; t < ksteps; ++t) {
        if (t + 2 < ksteps) {
            stageG(bufOff[(t + 2) % 3], (t + 2) << 7);
            asm volatile("s_waitcnt vmcnt(14)" ::: "memory");
        } else if (t + 1 < ksteps) {
            asm volatile("s_waitcnt vmcnt(7)" ::: "memory");
        } else {
            asm volatile("s_waitcnt vmcnt(0)" ::: "memory");
        }
        __builtin_amdgcn_s_barrier();
        __builtin_amdgcn_sched_barrier(0);
        computeG(bufOff[t % 3]);
        __builtin_amdgcn_sched_barrier(0);
        __builtin_amdgcn_s_barrier();
    }

    // fused gate elementwise: acc[g][r] = gh for (b = mt*16+q*4+r, jg = js+fr)
    const int jg = js + fr;
    const float bhr = b_hh[jg], bhz = b_hh[GDIM + jg], bhn = b_hh[2 * GDIM + jg];
    #pragma unroll
    for (int r = 0; r < 4; ++r) {
        int b = mt * 16 + q * 4 + r;
        const float* gi = gi_t + (size_t)b * G3 + jg;
        float hr = acc[0][r] + bhr;
        float hz = acc[1][r] + bhz;
        float hn = acc[2][r] + bhn;
        float rg = 1.f / (1.f + expf(-(gi[0]    + hr)));
        float zg = 1.f / (1.f + expf(-(gi[GDIM] + hz)));
        float ng = tanhf(gi[2 * GDIM] + rg * hn);
        float hp = hcur[(size_t)b * GDIM + jg];
        float hnew = (1.f - zg) * ng + zg * hp;
        hcur[(size_t)b * GDIM + jg] = hnew;
        unsigned short h1 = f2bf(hnew);
        unsigned short h2 = f2bf(hnew - bf2f(h1));
        short* ab = a_out + (size_t)b * G3 + jg;
        ab[0]        = (short)h1;
        ab[GDIM]     = (short)h2;
        ab[2 * GDIM] = (short)h1;
        hs_t[(size_t)b * GDIM + jg] = (short)h1;
    }
}

// ---------------------------------------------------------------------------
// launch
// ---------------------------------------------------------------------------
extern "C" void kernel_launch(void* const* d_in, const int* in_sizes, int n_in,
                              void* d_out, int out_size, void* d_ws, size_t ws_size,
                              hipStream_t stream)
{
    const float* features = (const float*)d_in[0];
    const int*   ids      = (const int*)  d_in[1];
    const float* emb      = (const float*)d_in[2];
    const float* img_v    = (const float*)d_in[3];
    const float* img_g    = (const float*)d_in[4];
    const float* img_b    = (const float*)d_in[5];
    const float* W_ih     = (const float*)d_in[6];
    const float* W_hh     = (const float*)d_in[7];
    const float* b_ih     = (const float*)d_in[8];
    const float* b_hh     = (const float*)d_in[9];
    const float* fc_v     = (const float*)d_in[10];
    const float* fc_g     = (const float*)d_in[11];
    const float* fc_b     = (const float*)d_in[12];
    float* out = (float*)d_out;
    float* ws  = (float*)d_ws;

    // workspace layout (float offsets)
    float* scale_img = ws;                          //       512
    float* scale_fc  = ws + 512;                    //    32,000
    short* hs_bf     = (short*)(ws + 32512);        //   655,360 f
    float* hcur      = ws + 687872;                 //    65,536
    short* a_buf0    = (short*)(ws + 753408);       //    98,304 f
    short* a_buf1    = (short*)(ws + 851712);       //    98,304 f
    short* Bcat      = (short*)(ws + 950016);       // 4,718,592 f
    float* x_all     = ws + 5668608;                //   655,360
    short* x_bf      = (short*)(ws + 6323968);      //   327,680 f
    short* wih_bf    = (short*)(ws + 6651648);      //   786,432 f
    float* gi_all    = ws + 7438080;                // 3,932,160  -> 11,370,240 f total
    // fcv_bf overlays Bcat..gi_all (dead after GRU): end 17,334,016 f = 66.1MB
    short* fcv_bf    = (short*)(ws + 950016);

    hipLaunchKernelGGL(scales_img_kernel, dim3(128), dim3(256), 0, stream,
                       img_v, img_g, scale_img);
    hipLaunchKernelGGL(img_embed_kernel, dim3(8192), dim3(256), 0, stream,
                       features, img_v, scale_img, img_b, x_all);
    hipLaunchKernelGGL(gather_kernel, dim3(2432), dim3(256), 0, stream,
                       ids, emb, x_all);
    hipLaunchKernelGGL(cvt_bf16_kernel, dim3((TSTEP * BATCH * EDIM / 4 + 255) / 256), dim3(256), 0, stream,
                       x_all, x_bf, TSTEP * BATCH * EDIM / 4);
    hipLaunchKernelGGL(cvt_bf16_kernel, dim3((G3 * EDIM / 4 + 255) / 256), dim3(256), 0, stream,
                       W_ih, wih_bf, G3 * EDIM / 4);
    hipLaunchKernelGGL(wcat_kernel, dim3(G3 * (GDIM / 4) / 256), dim3(256), 0, stream,
                       W_hh, Bcat);
    hipMemsetAsync(hcur, 0, (size_t)BATCH * GDIM * sizeof(float), stream);
    hipMemsetAsync(a_buf0, 0, (size_t)BATCH * G3 * sizeof(short), stream);

    // gi_all = x_bf @ wih_bf^T + b_ih   [1280, 3072]
    hipLaunchKernelGGL(mfma_gemm_kernel, dim3(G3 / 128, (TSTEP * BATCH) / 128, 1), dim3(256), 0, stream,
                       x_bf, wih_bf, gi_all, TSTEP * BATCH, G3, EDIM,
                       (const float*)nullptr, b_ih, 0);

    // GRU recurrence: one fused launch per step, a_buf ping-pong
    for (int t = 0; t < TSTEP; ++t) {
        short* a_in  = (t & 1) ? a_buf1 : a_buf0;
        short* a_out = (t & 1) ? a_buf0 : a_buf1;
        hipLaunchKernelGGL(gru_step3_kernel, dim3(64), dim3(256), 0, stream,
                           Bcat, a_in, a_out,
                           gi_all + (size_t)t * BATCH * G3, b_hh, hcur,
                           hs_bf + (size_t)t * BATCH * GDIM);
    }

    // fc_v norms + bf16 convert (after GRU: fcv_bf overlays dead region)
    hipLaunchKernelGGL(fc_norm_cvt_kernel, dim3(VDIM), dim3(256), 0, stream,
                       fc_v, fc_g, fcv_bf, scale_fc);

    // preds = (hs_bf @ fcv_bf^T) * scale_fc + fc_b, permuted [B,T,V] store
    hipLaunchKernelGGL(mfma_gemm256_kernel,
                       dim3((VDIM / 256) * ((TSTEP * BATCH) / 256)), dim3(512), 0, stream,
                       hs_bf, fcv_bf, out, TSTEP * BATCH, VDIM, GDIM,
                       scale_fc, fc_b, 1);
}

// Round 5
// 670.409 us; speedup vs baseline: 2.9067x; 1.4072x over previous
//
#include <hip/hip_runtime.h>
#include <hip/hip_bf16.h>
#include <math.h>

// Problem constants
#define BATCH 64
#define TSTEP 20
#define FDIM  2048
#define EDIM  512
#define GDIM  1024
#define G3    3072
#define VDIM  32000

typedef __attribute__((ext_vector_type(8))) short short8x;
typedef __attribute__((ext_vector_type(4))) float f32x4;

static __device__ __forceinline__ unsigned short f2bf(float f) {
    unsigned int u = __float_as_uint(f);
    unsigned int r = (u + 0x7fffu + ((u >> 16) & 1u)) >> 16;
    return (unsigned short)r;
}
static __device__ __forceinline__ float bf2f(unsigned short u) {
    return __uint_as_float((unsigned int)u << 16);
}

// ---------------------------------------------------------------------------
// scale_img[e] = img_g[e]/||img_v[e,:]||  (512 rows, one wave each)
// ---------------------------------------------------------------------------
__global__ __launch_bounds__(256) void scales_img_kernel(
    const float* __restrict__ img_v, const float* __restrict__ img_g,
    float* __restrict__ scale_img)
{
    int wave = blockIdx.x * 4 + (threadIdx.x >> 6);
    int lane = threadIdx.x & 63;
    const float* row = img_v + (size_t)wave * FDIM;
    float s = 0.f;
    for (int k = lane; k < FDIM; k += 64) { float v = row[k]; s = fmaf(v, v, s); }
    for (int off = 32; off; off >>= 1) s += __shfl_down(s, off);
    if (lane == 0) scale_img[wave] = img_g[wave] * (1.0f / sqrtf(s));
}

// ---------------------------------------------------------------------------
// fc row norm + bf16 convert fused: one block per row of fc_v [V,1024].
// Output written TILED: [nt=V/256][kt=K/64][256 rows][64 cols] so each GEMM
// K-step's 32KB B-block is contiguous in memory (DRAM-stream friendly).
// ---------------------------------------------------------------------------
__global__ __launch_bounds__(256) void fc_norm_cvt_kernel(
    const float* __restrict__ fc_v, const float* __restrict__ fc_g,
    short* __restrict__ v_bf, float* __restrict__ scale_fc)
{
    int row = blockIdx.x;
    int t = threadIdx.x;
    float4 v = ((const float4*)(fc_v + (size_t)row * GDIM))[t];
    short4 o;
    o.x = (short)f2bf(v.x); o.y = (short)f2bf(v.y);
    o.z = (short)f2bf(v.z); o.w = (short)f2bf(v.w);
    int nt = row >> 8, rloc = row & 255;
    int kt = t >> 4, kl = (t & 15) << 2;
    *(short4*)(v_bf + (size_t)nt * 262144 + (size_t)(kt * 256 + rloc) * 64 + kl) = o;
    float ss = v.x * v.x + v.y * v.y + v.z * v.z + v.w * v.w;
    for (int off = 32; off; off >>= 1) ss += __shfl_down(ss, off);
    __shared__ float red[4];
    if ((t & 63) == 0) red[t >> 6] = ss;
    __syncthreads();
    if (t == 0) {
        float s = red[0] + red[1] + red[2] + red[3];
        scale_fc[row] = fc_g[row] * (1.0f / sqrtf(s));
    }
}

// ---------------------------------------------------------------------------
// generic fp32 -> bf16 convert (n must be divisible by 4)
// ---------------------------------------------------------------------------
__global__ __launch_bounds__(256) void cvt_bf16_kernel(
    const float* __restrict__ in, short* __restrict__ out, int n4)
{
    int i = blockIdx.x * 256 + threadIdx.x;
    if (i >= n4) return;
    float4 v = ((const float4*)in)[i];
    short4 o;
    o.x = (short)f2bf(v.x); o.y = (short)f2bf(v.y);
    o.z = (short)f2bf(v.z); o.w = (short)f2bf(v.w);
    ((short4*)out)[i] = o;
}

// ---------------------------------------------------------------------------
// Bcat precompute: Bcat[j] = [W1[j,:] | W1[j,:] | W2[j,:]] (bf16 split of W_hh)
// ---------------------------------------------------------------------------
__global__ __launch_bounds__(256) void wcat_kernel(
    const float* __restrict__ W_hh, short* __restrict__ Bcat)
{
    int idx = blockIdx.x * 256 + threadIdx.x;   // 3072 * 256
    int j = idx >> 8;
    int k = (idx & 255) << 2;
    float4 w = *(const float4*)(W_hh + (size_t)j * GDIM + k);
    short4 s1, s2;
    s1.x = (short)f2bf(w.x); s2.x = (short)f2bf(w.x - bf2f((unsigned short)s1.x));
    s1.y = (short)f2bf(w.y); s2.y = (short)f2bf(w.y - bf2f((unsigned short)s1.y));
    s1.z = (short)f2bf(w.z); s2.z = (short)f2bf(w.z - bf2f((unsigned short)s1.z));
    s1.w = (short)f2bf(w.w); s2.w = (short)f2bf(w.w - bf2f((unsigned short)s1.w));
    short* row = Bcat + (size_t)j * G3;
    *(short4*)(row + k)        = s1;
    *(short4*)(row + 1024 + k) = s1;
    *(short4*)(row + 2048 + k) = s2;
}

// ---------------------------------------------------------------------------
// img_embed
// ---------------------------------------------------------------------------
__global__ __launch_bounds__(256) void img_embed_kernel(
    const float* __restrict__ features, const float* __restrict__ img_v,
    const float* __restrict__ scale_img, const float* __restrict__ img_b,
    float* __restrict__ x_all)
{
    int wave = blockIdx.x * 4 + (threadIdx.x >> 6);
    int lane = threadIdx.x & 63;
    int b = wave >> 9;
    int e = wave & 511;
    const float* frow = features + (size_t)b * FDIM;
    const float* vrow = img_v + (size_t)e * FDIM;
    float s = 0.f;
    for (int k = lane; k < FDIM; k += 64) s = fmaf(frow[k], vrow[k], s);
    for (int off = 32; off; off >>= 1) s += __shfl_down(s, off);
    if (lane == 0) x_all[b * EDIM + e] = s * scale_img[e] + img_b[e];
}

// ---------------------------------------------------------------------------
// gather: x_all[t][b][:] = emb_table[input_ids[b][t]] for t = 1..19
// ---------------------------------------------------------------------------
__global__ __launch_bounds__(256) void gather_kernel(
    const int* __restrict__ ids, const float* __restrict__ emb,
    float* __restrict__ x_all)
{
    int idx = blockIdx.x * 256 + threadIdx.x;
    int e = idx & 511;
    int b = (idx >> 9) & 63;
    int t = (idx >> 15) + 1;
    int id = ids[b * TSTEP + t];
    x_all[(size_t)(t * BATCH + b) * EDIM + e] = emb[(size_t)id * EDIM + e];
}

// ---------------------------------------------------------------------------
// bf16 MFMA GEMM, 128x128 tile (used for the gi GEMM)
// ---------------------------------------------------------------------------
__global__ __launch_bounds__(256) void mfma_gemm_kernel(
    const short* __restrict__ A, const short* __restrict__ B,
    float* __restrict__ C, int M, int N, int K,
    const float* __restrict__ scale, const float* __restrict__ bias,
    int out_mode)
{
    __shared__ short As[128 * 32];
    __shared__ short Bs[128 * 32];

    const int tid  = threadIdx.x;
    const int wave = tid >> 6;
    const int lane = tid & 63;
    const int m0 = blockIdx.y * 128;
    const int n0 = blockIdx.x * 128;

    const int srow   = lane >> 2;
    const int schunk = (lane & 3) ^ ((lane >> 3) & 3);

    const int wm = wave >> 1, wn = wave & 1;
    const int fr = lane & 15;
    const int q  = lane >> 4;
    const int kchunk = (q ^ ((fr >> 1) & 3)) * 8;

    f32x4 acc[4][4];
    #pragma unroll
    for (int i = 0; i < 4; ++i)
        #pragma unroll
        for (int j = 0; j < 4; ++j)
            acc[i][j] = (f32x4)(0.f);

    for (int k0 = 0; k0 < K; k0 += 32) {
        __syncthreads();
        #pragma unroll
        for (int p = 0; p < 2; ++p) {
            int mi = wave * 2 + p;
            int rA = mi * 16 + srow;
            const short* gA = A + (size_t)(m0 + rA) * K + k0 + schunk * 8;
            const short* gB = B + (size_t)(n0 + rA) * K + k0 + schunk * 8;
            __builtin_amdgcn_global_load_lds(
                (const __attribute__((address_space(1))) void*)gA,
                (__attribute__((address_space(3))) void*)(As + mi * 512), 16, 0, 0);
            __builtin_amdgcn_global_load_lds(
                (const __attribute__((address_space(1))) void*)gB,
                (__attribute__((address_space(3))) void*)(Bs + mi * 512), 16, 0, 0);
        }
        __syncthreads();

        short8x a[4], b[4];
        #pragma unroll
        for (int i = 0; i < 4; ++i)
            a[i] = *(const short8x*)(As + (wm * 64 + i * 16 + fr) * 32 + kchunk);
        #pragma unroll
        for (int j = 0; j < 4; ++j)
            b[j] = *(const short8x*)(Bs + (wn * 64 + j * 16 + fr) * 32 + kchunk);
        #pragma unroll
        for (int i = 0; i < 4; ++i)
            #pragma unroll
            for (int j = 0; j < 4; ++j)
                acc[i][j] = __builtin_amdgcn_mfma_f32_16x16x32_bf16(a[i], b[j], acc[i][j], 0, 0, 0);
    }

    #pragma unroll
    for (int i = 0; i < 4; ++i) {
        #pragma unroll
        for (int r = 0; r < 4; ++r) {
            int m = m0 + wm * 64 + i * 16 + q * 4 + r;
            #pragma unroll
            for (int j = 0; j < 4; ++j) {
                int n = n0 + wn * 64 + j * 16 + fr;
                float v = acc[i][j][r];
                if (scale) v *= scale[n];
                if (bias)  v += bias[n];
                if (out_mode == 0) {
                    C[(size_t)m * N + n] = v;
                } else {
                    C[(size_t)(m & 63) * (TSTEP * N) + (size_t)(m >> 6) * N + n] = v;
                }
            }
        }
    }
}

// ---------------------------------------------------------------------------
// fc GEMM: 256x256 tile, BK=64, 512 threads, counted-vmcnt 2-buffer pipeline.
// B comes from the tiled layout [125][16][256][64] -> each K-step's B stage
// is one contiguous 32KB block. out is permuted [B,T,V] with scale+bias.
// ---------------------------------------------------------------------------
__global__ __launch_bounds__(512, 2) void mfma_gemm256_kernel(
    const short* __restrict__ A, const short* __restrict__ Bt,
    float* __restrict__ C, int M, int N, int K,
    const float* __restrict__ scale, const float* __restrict__ bias)
{
    __shared__ short As[2][256 * 64];
    __shared__ short Bs[2][256 * 64];

    const int tid = threadIdx.x;
    const int mtiles = M >> 8;
    const int nwg = gridDim.x;

    int wgid;
    {
        int q = nwg >> 3, r = nwg & 7;
        int xcd = blockIdx.x & 7, idx = blockIdx.x >> 3;
        wgid = (xcd < r ? xcd * (q + 1) : r * (q + 1) + (xcd - r) * q) + idx;
    }
    const int mt = wgid % mtiles;
    const int nt = wgid / mtiles;
    const int m0 = mt << 8, n0 = nt << 8;

    const int schunk = (tid & 7) ^ ((tid >> 3) & 7);
    const short* gA  = A  + (size_t)(m0 + (tid >> 3)) * K + schunk * 8;
    const short* gBt = Bt + (size_t)nt * 262144 + (size_t)(tid >> 3) * 64 + schunk * 8;

    const int wv = tid >> 6, lane = tid & 63;
    const int sbase = wv * 512;

    const int wm = wv >> 2, wn = wv & 3;
    const int fr = lane & 15, qd = lane >> 4;
    const int key = fr & 7;
    int aoff[2], boff[2];
    #pragma unroll
    for (int kk = 0; kk < 2; ++kk) {
        int slot = ((kk << 2) | qd) ^ key;
        aoff[kk] = (wm * 128 + fr) * 64 + (slot << 3);
        boff[kk] = (wn * 64 + fr) * 64 + (slot << 3);
    }

    f32x4 acc[8][4];
    #pragma unroll
    for (int i = 0; i < 8; ++i)
        #pragma unroll
        for (int j = 0; j < 4; ++j)
            acc[i][j] = (f32x4)(0.f);

    auto stage = [&](int buf, int t) {
        const int koffA = t << 6;               // shorts
        const size_t koffB = (size_t)t << 14;   // 16384 shorts per K-step
        #pragma unroll
        for (int rho = 0; rho < 4; ++rho) {
            __builtin_amdgcn_global_load_lds(
                (const __attribute__((address_space(1))) void*)(gA + (size_t)(rho * 64) * K + koffA),
                (__attribute__((address_space(3))) void*)(&As[buf][0] + rho * 4096 + sbase), 16, 0, 0);
            __builtin_amdgcn_global_load_lds(
                (const __attribute__((address_space(1))) void*)(gBt + (size_t)rho * 4096 + koffB),
                (__attribute__((address_space(3))) void*)(&Bs[buf][0] + rho * 4096 + sbase), 16, 0, 0);
        }
    };

    auto compute = [&](int buf) {
        const short* Ab = &As[buf][0];
        const short* Bb = &Bs[buf][0];
        #pragma unroll
        for (int kk = 0; kk < 2; ++kk) {
            short8x a[8], b[4];
            #pragma unroll
            for (int i = 0; i < 8; ++i) a[i] = *(const short8x*)(Ab + aoff[kk] + i * 1024);
            #pragma unroll
            for (int j = 0; j < 4; ++j) b[j] = *(const short8x*)(Bb + boff[kk] + j * 1024);
            __builtin_amdgcn_s_setprio(1);
            #pragma unroll
            for (int i = 0; i < 8; ++i)
                #pragma unroll
                for (int j = 0; j < 4; ++j)
                    acc[i][j] = __builtin_amdgcn_mfma_f32_16x16x32_bf16(a[i], b[j], acc[i][j], 0, 0, 0);
            __builtin_amdgcn_s_setprio(0);
        }
    };

    const int ksteps = K >> 6;
    stage(0, 0);
    int cur = 0;
    for (int t = 0; t < ksteps; ++t) {
        if (t + 1 < ksteps) {
            stage(cur ^ 1, t + 1);
            asm volatile("s_waitcnt vmcnt(8)" ::: "memory");
        } else {
            asm volatile("s_waitcnt vmcnt(0)" ::: "memory");
        }
        __builtin_amdgcn_s_barrier();
        __builtin_amdgcn_sched_barrier(0);
        compute(cur);
        __builtin_amdgcn_sched_barrier(0);
        __builtin_amdgcn_s_barrier();
        cur ^= 1;
    }

    #pragma unroll
    for (int i = 0; i < 8; ++i) {
        #pragma unroll
        for (int r2 = 0; r2 < 4; ++r2) {
            int m = m0 + wm * 128 + i * 16 + qd * 4 + r2;
            size_t rowbase = (size_t)(m & 63) * (TSTEP * N) + (size_t)(m >> 6) * N;
            #pragma unroll
            for (int j = 0; j < 4; ++j) {
                int n = n0 + wn * 64 + j * 16 + fr;
                C[rowbase + n] = acc[i][j][r2] * scale[n] + bias[n];
            }
        }
    }
}

// ===========================================================================
// GRU step v4 (LDS-hardened): full-chip, barrier-free K-loop.
// Grid 256 blocks x 256 threads: bid&63 = j-group (16 j x 3 gates = 48 B rows,
// pinned per-XCD via bid%8 -> 2.4MB Bcat slice stays L2-resident across all
// 20 launches), bid>>6 = batch quarter (16 A rows).
// Waves K-split (768 cols each): each wave has its own dbuf LDS region and
// its own counted-vmcnt pipeline -> NO barriers in the K-loop. Tile = 64 rows
// (16 A + 48 B) x 128 cols staged per wave; 4 kk x 3 gate MFMAs per tile.
// XOR chunk swizzle slot^(row&15) pre-applied on global source, matching
// slot^fr on ds_read (conflict-free b128). End: cross-wave reduce through
// LDS OVERLAID on each wave's own dead stage buffer 0 (wave writes only its
// own region post-K-loop; one __syncthreads before cross-wave reads) -> total
// LDS exactly 128 KB (the proven-working allocation).
// ===========================================================================
__global__ __launch_bounds__(256) void gru_step4_kernel(
    const short* __restrict__ Bcat, const short* __restrict__ a_in,
    short* __restrict__ a_out, const float* __restrict__ gi_t,
    const float* __restrict__ b_hh, float* __restrict__ hcur,
    short* __restrict__ hs_t)
{
    __shared__ short stagebuf[4][2][8192];   // 128 KB: wave x dbuf x (64x128)

    const int tid = threadIdx.x;
    const int bid = blockIdx.x;
    const int jg = bid & 63;
    const int mq = bid >> 6;
    const int wv = tid >> 6, lane = tid & 63;
    const int fr = lane & 15, q = lane >> 4;
    const int kw = wv * 768;

    // staging sources: 16 chunks of 16B per lane per 64x128 tile
    const short* srcp[16];
    #pragma unroll
    for (int i = 0; i < 16; ++i) {
        int c = i * 64 + lane;
        int row = c >> 4, slot = c & 15;
        int scol = kw + ((slot ^ (row & 15)) << 3);
        if (row < 16) {
            srcp[i] = a_in + (size_t)(mq * 16 + row) * G3 + scol;
        } else {
            int rb = row - 16, g = rb >> 4, jl = rb & 15;
            srcp[i] = Bcat + (size_t)(g * GDIM + jg * 16 + jl) * G3 + scol;
        }
    }

    short* my0 = &stagebuf[wv][0][0];
    short* my1 = &stagebuf[wv][1][0];

    auto stageW = [&](short* buf, int kb) {
        #pragma unroll
        for (int i = 0; i < 16; ++i) {
            __builtin_amdgcn_global_load_lds(
                (const __attribute__((address_space(1))) void*)(srcp[i] + kb),
                (__attribute__((address_space(3))) void*)(buf + (i << 9)), 16, 0, 0);
        }
    };

    int aoff[4], boff[3][4];
    #pragma unroll
    for (int kk = 0; kk < 4; ++kk) {
        int slot = ((kk << 2) | q) ^ fr;
        aoff[kk] = fr * 128 + (slot << 3);
        #pragma unroll
        for (int g = 0; g < 3; ++g)
            boff[g][kk] = (16 + g * 16 + fr) * 128 + (slot << 3);
    }

    f32x4 acc[3];
    acc[0] = (f32x4)(0.f); acc[1] = (f32x4)(0.f); acc[2] = (f32x4)(0.f);

    auto computeW = [&](const short* buf) {
        __builtin_amdgcn_s_setprio(1);
        #pragma unroll
        for (int kk = 0; kk < 4; ++kk) {
            short8x av = *(const short8x*)(buf + aoff[kk]);
            #pragma unroll
            for (int g = 0; g < 3; ++g) {
                short8x bv = *(const short8x*)(buf + boff[g][kk]);
                acc[g] = __builtin_amdgcn_mfma_f32_16x16x32_bf16(av, bv, acc[g], 0, 0, 0);
            }
        }
        __builtin_amdgcn_s_setprio(0);
    };

    stageW(my0, 0);
    stageW(my1, 128);
    #pragma unroll
    for (int t = 0; t < 6; ++t) {
        if (t < 5) { asm volatile("s_waitcnt vmcnt(16)" ::: "memory"); }
        else       { asm volatile("s_waitcnt vmcnt(0)"  ::: "memory"); }
        __builtin_amdgcn_sched_barrier(0);
        const short* buf = (t & 1) ? my1 : my0;
        computeW(buf);
        if (t + 2 < 6) stageW((short*)buf, (t + 2) << 7);
    }

    // cross-wave K-slice reduce via LDS overlaid on my0 (dead after t=4;
    // final compute at t=5 read my1). Each wave writes ONLY its own region.
    float* rb = (float*)my0;                 // [3][64][4] floats = 3 KB used
    #pragma unroll
    for (int g = 0; g < 3; ++g)
        #pragma unroll
        for (int r = 0; r < 4; ++r)
            rb[(g * 64 + lane) * 4 + r] = acc[g][r];
    __syncthreads();

    // fused gate elementwise: 256 threads = 16 b x 16 j
    const int bl = tid >> 4, jl = tid & 15;
    const int ln = ((bl >> 2) << 4) | jl;
    const int rr = bl & 3;
    const int b = mq * 16 + bl;
    const int j = jg * 16 + jl;
    float gh[3];
    #pragma unroll
    for (int g = 0; g < 3; ++g) {
        gh[g] = 0.f;
        #pragma unroll
        for (int w = 0; w < 4; ++w)
            gh[g] += ((const float*)(&stagebuf[w][0][0]))[(g * 64 + ln) * 4 + rr];
    }
    const float* gi = gi_t + (size_t)b * G3 + j;
    float hr = gh[0] + b_hh[j];
    float hz = gh[1] + b_hh[GDIM + j];
    float hn = gh[2] + b_hh[2 * GDIM + j];
    float rg = 1.f / (1.f + expf(-(gi[0]        + hr)));
    float zg = 1.f / (1.f + expf(-(gi[GDIM]     + hz)));
    float ng = tanhf(gi[2 * GDIM] + rg * hn);
    float hp = hcur[(size_t)b * GDIM + j];
    float hnew = (1.f - zg) * ng + zg * hp;
    hcur[(size_t)b * GDIM + j] = hnew;
    unsigned short h1 = f2bf(hnew);
    unsigned short h2 = f2bf(hnew - bf2f(h1));
    short* ab = a_out + (size_t)b * G3 + j;
    ab[0]        = (short)h1;
    ab[GDIM]     = (short)h2;
    ab[2 * GDIM] = (short)h1;
    hs_t[(size_t)b * GDIM + j] = (short)h1;
}

// ---------------------------------------------------------------------------
// launch
// ---------------------------------------------------------------------------
extern "C" void kernel_launch(void* const* d_in, const int* in_sizes, int n_in,
                              void* d_out, int out_size, void* d_ws, size_t ws_size,
                              hipStream_t stream)
{
    const float* features = (const float*)d_in[0];
    const int*   ids      = (const int*)  d_in[1];
    const float* emb      = (const float*)d_in[2];
    const float* img_v    = (const float*)d_in[3];
    const float* img_g    = (const float*)d_in[4];
    const float* img_b    = (const float*)d_in[5];
    const float* W_ih     = (const float*)d_in[6];
    const float* W_hh     = (const float*)d_in[7];
    const float* b_ih     = (const float*)d_in[8];
    const float* b_hh     = (const float*)d_in[9];
    const float* fc_v     = (const float*)d_in[10];
    const float* fc_g     = (const float*)d_in[11];
    const float* fc_b     = (const float*)d_in[12];
    float* out = (float*)d_out;
    float* ws  = (float*)d_ws;

    // workspace layout (float offsets)
    float* scale_img = ws;                          //       512
    float* scale_fc  = ws + 512;                    //    32,000
    short* hs_bf     = (short*)(ws + 32512);        //   655,360 f
    float* hcur      = ws + 687872;                 //    65,536
    short* a_buf0    = (short*)(ws + 753408);       //    98,304 f
    short* a_buf1    = (short*)(ws + 851712);       //    98,304 f
    short* Bcat      = (short*)(ws + 950016);       // 4,718,592 f
    float* x_all     = ws + 5668608;                //   655,360
    short* x_bf      = (short*)(ws + 6323968);      //   327,680 f
    short* wih_bf    = (short*)(ws + 6651648);      //   786,432 f
    float* gi_all    = ws + 7438080;                // 3,932,160
    // fcv_bf overlays Bcat..gi_all (dead after GRU)
    short* fcv_bf    = (short*)(ws + 950016);       // 32,768,000 sh (tiled)

    hipLaunchKernelGGL(scales_img_kernel, dim3(128), dim3(256), 0, stream,
                       img_v, img_g, scale_img);
    hipLaunchKernelGGL(img_embed_kernel, dim3(8192), dim3(256), 0, stream,
                       features, img_v, scale_img, img_b, x_all);
    hipLaunchKernelGGL(gather_kernel, dim3(2432), dim3(256), 0, stream,
                       ids, emb, x_all);
    hipLaunchKernelGGL(cvt_bf16_kernel, dim3((TSTEP * BATCH * EDIM / 4 + 255) / 256), dim3(256), 0, stream,
                       x_all, x_bf, TSTEP * BATCH * EDIM / 4);
    hipLaunchKernelGGL(cvt_bf16_kernel, dim3((G3 * EDIM / 4 + 255) / 256), dim3(256), 0, stream,
                       W_ih, wih_bf, G3 * EDIM / 4);
    hipLaunchKernelGGL(wcat_kernel, dim3(G3 * (GDIM / 4) / 256), dim3(256), 0, stream,
                       W_hh, Bcat);
    hipMemsetAsync(hcur, 0, (size_t)BATCH * GDIM * sizeof(float), stream);
    hipMemsetAsync(a_buf0, 0, (size_t)BATCH * G3 * sizeof(short), stream);

    // gi_all = x_bf @ wih_bf^T + b_ih   [1280, 3072]
    hipLaunchKernelGGL(mfma_gemm_kernel, dim3(G3 / 128, (TSTEP * BATCH) / 128, 1), dim3(256), 0, stream,
                       x_bf, wih_bf, gi_all, TSTEP * BATCH, G3, EDIM,
                       (const float*)nullptr, b_ih, 0);

    // GRU recurrence: one full-chip launch per step, a_buf ping-pong
    for (int t = 0; t < TSTEP; ++t) {
        short* a_in  = (t & 1) ? a_buf1 : a_buf0;
        short* a_out = (t & 1) ? a_buf0 : a_buf1;
        hipLaunchKernelGGL(gru_step4_kernel, dim3(256), dim3(256), 0, stream,
                           Bcat, a_in, a_out,
                           gi_all + (size_t)t * BATCH * G3, b_hh, hcur,
                           hs_bf + (size_t)t * BATCH * GDIM);
    }

    // fc_v norms + tiled bf16 convert (fcv_bf overlays dead region)
    hipLaunchKernelGGL(fc_norm_cvt_kernel, dim3(VDIM), dim3(256), 0, stream,
                       fc_v, fc_g, fcv_bf, scale_fc);

    // preds = (hs_bf @ fcv^T) * scale_fc + fc_b, permuted [B,T,V] store
    hipLaunchKernelGGL(mfma_gemm256_kernel,
                       dim3((VDIM / 256) * ((TSTEP * BATCH) / 256)), dim3(512), 0, stream,
                       hs_bf, fcv_bf, out, TSTEP * BATCH, VDIM, GDIM,
                       scale_fc, fc_b);
}